// Round 14
// baseline (260.235 us; speedup 1.0000x reference)
//
#include <hip/hip_runtime.h>

#define N_NODES 100000
#define N_EDGES 1600000
#define D 128
#define SUBW 32                       // dst-nodes per agg sub-block
#define NSUB2 3125                    // 100000/32 exact
#define AGG_HALF 1563                 // aggA blocks (aggB = 1562)
#define NC 196                        // coarse buckets of 512 nodes (dst>>9)
#define BSH 9                         // bucket shift
#define BMSK 511                      // bucket mask
#define CAPC 12288                    // per-bucket raw cap: 8163 mean + 2932 mean pad + 8 sigma(123)
#define CAP3 9728                     // per-bucket sorted cap: 8163 + 17 sigma(90), %16==0
#define CAPS2 1024                    // per-sub staged slice cap (mean 512, +22 sigma)
#define CHUNK3 4096                   // edges per binD block
#define BIND_BLOCKS ((N_EDGES + CHUNK3 - 1) / CHUNK3)   // 391
#define GEMM_BLOCKS ((N_NODES + 127) / 128)             // 782 (128 rows / 512-thr block)
#define STAGE_MAX (CHUNK3 + NC * 16)  // 7232 staging slots (claims padded to 16)
#define NGRP (STAGE_MAX / 16)         // 452 16-slot groups
#define CCSTRIDE 16                   // ccnt padded to one 64B line per bucket

typedef __attribute__((ext_vector_type(8))) short short8;
typedef __attribute__((ext_vector_type(4))) float float4v;

__device__ inline unsigned short f2bf(float f) {
    unsigned u = __float_as_uint(f);
    unsigned r = (u + 0x7fffu + ((u >> 16) & 1u)) >> 16;   // RNE
    return (unsigned short)r;
}
__device__ inline float bflo(unsigned int p) { return __uint_as_float(p << 16); }
__device__ inline float bfhi(unsigned int p) { return __uint_as_float(p & 0xffff0000u); }

// dtype probe + b->fp32 + W->bf16 pre-convert + ccnt zeroing
__global__ void probe_convert_kernel(const unsigned int* __restrict__ xw,
                                     const void* __restrict__ b,
                                     const void* __restrict__ Wv,
                                     int* __restrict__ flag, float* __restrict__ bfv,
                                     unsigned short* __restrict__ Wbf,
                                     int* __restrict__ ccnt) {
    __shared__ int cnt;
    if (threadIdx.x == 0) cnt = 0;
    __syncthreads();
    unsigned low = xw[threadIdx.x] & 0xFFFFu;
    unsigned e = (low >> 7) & 0xFFu;
    atomicAdd(&cnt, (int)((e == 0u) || (e >= 107u && e <= 147u)));
    __syncthreads();
    int m = (cnt >= 192);
    if (threadIdx.x == 0) *flag = m;
    if (threadIdx.x < D)
        bfv[threadIdx.x] = m ? bflo(((const unsigned short*)b)[threadIdx.x])
                             : ((const float*)b)[threadIdx.x];
    for (int i = threadIdx.x; i < D * D; i += 256)
        Wbf[i] = m ? ((const unsigned short*)Wv)[i] : f2bf(((const float*)Wv)[i]);
    for (int i = threadIdx.x; i < NC * CCSTRIDE; i += 256) ccnt[i] = 0;
}

// R14 MEASUREMENT ROUND: every stage de-fused so rocprof shows per-kernel time.
// binD standalone, 512 thr, 8 edges/thread; LUT flush.
__global__ void __launch_bounds__(512) binD_kernel(
        const int* __restrict__ src, const int* __restrict__ dst,
        int* __restrict__ ccnt, unsigned* __restrict__ recg) {
    __shared__ __align__(16) unsigned stg[STAGE_MAX];   // 28.9 KB
    __shared__ int cnt[NC], cpad[NC], ofs[NC], base[NC], place[NC];
    __shared__ unsigned short g2b[NGRP];
    __shared__ int tot;

    int tid = threadIdx.x;
    int e0 = blockIdx.x * CHUNK3;
    int e1 = e0 + CHUNK3 < N_EDGES ? e0 + CHUNK3 : N_EDGES;
    if (tid < NC) cnt[tid] = 0;
    __syncthreads();

    unsigned recs[8];
    int bks[8];
    #pragma unroll
    for (int k = 0; k < 2; ++k) {
        int i = e0 + tid * 4 + k * 2048;
        if (i + 3 < e1) {
            int4 d4 = *(const int4*)&dst[i];
            int4 s4 = *(const int4*)&src[i];
            recs[k * 4 + 0] = (unsigned)s4.x | ((unsigned)(d4.x & BMSK) << 17); bks[k * 4 + 0] = d4.x >> BSH;
            recs[k * 4 + 1] = (unsigned)s4.y | ((unsigned)(d4.y & BMSK) << 17); bks[k * 4 + 1] = d4.y >> BSH;
            recs[k * 4 + 2] = (unsigned)s4.z | ((unsigned)(d4.z & BMSK) << 17); bks[k * 4 + 2] = d4.z >> BSH;
            recs[k * 4 + 3] = (unsigned)s4.w | ((unsigned)(d4.w & BMSK) << 17); bks[k * 4 + 3] = d4.w >> BSH;
        } else {
            bks[k * 4 + 0] = -1; bks[k * 4 + 1] = -1; bks[k * 4 + 2] = -1; bks[k * 4 + 3] = -1;
            recs[k * 4 + 0] = 0; recs[k * 4 + 1] = 0; recs[k * 4 + 2] = 0; recs[k * 4 + 3] = 0;
        }
    }
    #pragma unroll
    for (int k = 0; k < 8; ++k)
        if (bks[k] >= 0) atomicAdd(&cnt[bks[k]], 1);
    __syncthreads();

    if (tid < NC) {
        int c = cnt[tid];
        int p = (c + 15) & ~15;
        cpad[tid] = p;
        base[tid] = p ? atomicAdd(&ccnt[tid * CCSTRIDE], p) : 0;
    }
    __syncthreads();
    if (tid == 0) {
        int s = 0;
        for (int k = 0; k < NC; ++k) { ofs[k] = s; place[k] = s; s += cpad[k]; }
        tot = s;
    }
    __syncthreads();
    if (tid < NC) {
        int o = ofs[tid], e = o + cpad[tid];
        for (int j = o + cnt[tid]; j < e; ++j) stg[j] = 0xFFFFFFFFu;
        for (int g = o >> 4; g < (e >> 4); ++g) g2b[g] = (unsigned short)tid;
    }
    __syncthreads();

    #pragma unroll
    for (int k = 0; k < 8; ++k)
        if (bks[k] >= 0) {
            int p = atomicAdd(&place[bks[k]], 1);
            stg[p] = recs[k];
        }
    __syncthreads();

    int tot_ = tot;
    for (int j = tid * 4; j < tot_; j += 2048) {
        int lo = g2b[j >> 4];                            // 1 LDS read
        int gi = base[lo] + (j - ofs[lo]);
        if (gi < CAPC)
            *(uint4*)&recg[(size_t)lo * CAPC + gi] = *(const uint4*)&stg[j];
    }
}

// gemm standalone, 512 thr, 128 rows/block, swapped-operand MFMA + uint2 stores (R13).
__global__ void __launch_bounds__(512) gemm_kernel(
        const void* __restrict__ xv, const unsigned short* __restrict__ Wbf,
        const int* __restrict__ flag, unsigned short* __restrict__ h) {
    __shared__ unsigned short Wt[D * 136];               // 34.8 KB
    int tid = threadIdx.x;
    int m = *flag;
    for (int idx = tid; idx < D * D; idx += 512) {
        int k = idx >> 7, c = idx & 127;
        Wt[c * 136 + k] = Wbf[idx];
    }
    __syncthreads();

    int wave = tid >> 6, lane = tid & 63;
    int row0 = (int)blockIdx.x * 128 + wave * 16;
    if (row0 >= N_NODES) return;
    int r = lane & 15, quad = lane >> 4;

    short8 a[4];  // B-frag: x[row0+r][t*32 + quad*8 + j]
    if (m) {
        const unsigned short* xr = (const unsigned short*)xv + (size_t)(row0 + r) * D + quad * 8;
        #pragma unroll
        for (int t = 0; t < 4; ++t) a[t] = *(const short8*)(xr + t * 32);
    } else {
        const float* xr = (const float*)xv + (size_t)(row0 + r) * D + quad * 8;
        #pragma unroll
        for (int t = 0; t < 4; ++t) {
            float4 f0 = *(const float4*)(xr + t * 32);
            float4 f1 = *(const float4*)(xr + t * 32 + 4);
            a[t][0] = (short)f2bf(f0.x); a[t][1] = (short)f2bf(f0.y);
            a[t][2] = (short)f2bf(f0.z); a[t][3] = (short)f2bf(f0.w);
            a[t][4] = (short)f2bf(f1.x); a[t][5] = (short)f2bf(f1.y);
            a[t][6] = (short)f2bf(f1.z); a[t][7] = (short)f2bf(f1.w);
        }
    }

    #pragma unroll
    for (int ct = 0; ct < 8; ++ct) {
        int col0 = ct * 16;
        float4v c4 = {0.f, 0.f, 0.f, 0.f};
        #pragma unroll
        for (int t = 0; t < 4; ++t) {
            short8 bfr = *(const short8*)&Wt[(col0 + r) * 136 + t * 32 + quad * 8];
            c4 = __builtin_amdgcn_mfma_f32_16x16x32_bf16(bfr, a[t], c4, 0, 0, 0);
        }
        unsigned u0 = (unsigned)f2bf(c4[0]) | ((unsigned)f2bf(c4[1]) << 16);
        unsigned u1 = (unsigned)f2bf(c4[2]) | ((unsigned)f2bf(c4[3]) << 16);
        *(uint2*)&h[(size_t)(row0 + r) * D + col0 + quad * 4] = make_uint2(u0, u1);
    }
}

// sortdeg standalone, 512 thr, one 512-node bucket per block.
__global__ void __launch_bounds__(512) sortdeg_kernel(
        unsigned* __restrict__ recg, const int* __restrict__ ccnt,
        int* __restrict__ deg, int* __restrict__ nodeofs, float* __restrict__ dis) {
    __shared__ int hist[512];
    __shared__ int ofs[512];
    __shared__ int place[512];
    __shared__ int wsum[8];
    __shared__ __align__(16) unsigned s_srt[CAP3];       // 38.9 KB

    int b = blockIdx.x, tid = threadIdx.x;
    hist[tid] = 0;
    __syncthreads();
    int count = ccnt[b * CCSTRIDE]; if (count > CAPC) count = CAPC;
    const unsigned* r = recg + (size_t)b * CAPC;
    for (int i = tid * 4; i + 3 < count; i += 2048) {    // count % 16 == 0
        uint4 w4 = *(const uint4*)&r[i];
        if (w4.x != 0xFFFFFFFFu) atomicAdd(&hist[w4.x >> 17], 1);
        if (w4.y != 0xFFFFFFFFu) atomicAdd(&hist[w4.y >> 17], 1);
        if (w4.z != 0xFFFFFFFFu) atomicAdd(&hist[w4.z >> 17], 1);
        if (w4.w != 0xFFFFFFFFu) atomicAdd(&hist[w4.w >> 17], 1);
    }
    __syncthreads();

    int lane = tid & 63, wave = tid >> 6;
    int h0 = hist[tid];
    int v = h0;
    #pragma unroll
    for (int dsh = 1; dsh < 64; dsh <<= 1) {
        int uu = __shfl_up(v, dsh);
        if (lane >= dsh) v += uu;
    }
    if (lane == 63) wsum[wave] = v;
    __syncthreads();
    int wbase = 0;
    #pragma unroll
    for (int k = 0; k < 8; ++k) if (k < wave) wbase += wsum[k];
    int e0v = wbase + v - h0;
    ofs[tid] = e0v; place[tid] = e0v;
    int n = b * 512 + tid;
    deg[n] = h0;
    nodeofs[n] = e0v;
    dis[n] = rsqrtf((float)(h0 + 1));
    __syncthreads();

    for (int i = tid * 4; i + 3 < count; i += 2048) {
        uint4 w4 = *(const uint4*)&r[i];
        if (w4.x != 0xFFFFFFFFu) { int p = atomicAdd(&place[w4.x >> 17], 1); if (p < CAP3) s_srt[p] = w4.x & 0x1FFFFu; }
        if (w4.y != 0xFFFFFFFFu) { int p = atomicAdd(&place[w4.y >> 17], 1); if (p < CAP3) s_srt[p] = w4.y & 0x1FFFFu; }
        if (w4.z != 0xFFFFFFFFu) { int p = atomicAdd(&place[w4.z >> 17], 1); if (p < CAP3) s_srt[p] = w4.z & 0x1FFFFu; }
        if (w4.w != 0xFFFFFFFFu) { int p = atomicAdd(&place[w4.w >> 17], 1); if (p < CAP3) s_srt[p] = w4.w & 0x1FFFFu; }
    }
    __syncthreads();

    int total = ofs[511] + hist[511];
    int totR = (total + 15) & ~15; if (totR > CAP3) totR = CAP3;
    unsigned* w = recg + (size_t)b * CAPC;
    for (int j = tid * 4; j < totR; j += 2048)
        *(uint4*)&w[j] = *(const uint4*)&s_srt[j];
}

// agg (R7 structure): one block per 32-node sub; grid is HALF of NSUB2 (sub0 offset)
// so agg no longer monopolizes the top-5 table — the slowest MID kernel becomes
// directly visible in rocprof this round.
__global__ void __launch_bounds__(256) agg5_kernel(
        const unsigned* __restrict__ srt2, const int* __restrict__ nodeofs,
        const int* __restrict__ deg, const float* __restrict__ dis,
        const float* __restrict__ bfv, const int* __restrict__ flag,
        const unsigned short* __restrict__ h, void* __restrict__ out, int sub0) {
    __shared__ unsigned srt[CAPS2];    // 4 KB
    __shared__ int l_ofs[SUBW];
    __shared__ int l_deg[SUBW];
    __shared__ float lbias[D];

    int sub = blockIdx.x + sub0, tid = threadIdx.x;
    int n0 = sub * SUBW;               // NSUB2*SUBW == N_NODES exactly, no tail
    int B = n0 >> BSH, loc0 = n0 & BMSK;
    if (tid < SUBW) {
        l_ofs[tid] = nodeofs[B * 512 + loc0 + tid];
        l_deg[tid] = deg[n0 + tid];
    }
    if (tid < D) lbias[tid] = bfv[tid];
    __syncthreads();

    int base0 = l_ofs[0];
    int span = (l_ofs[SUBW - 1] + l_deg[SUBW - 1]) - base0;
    if (span > CAPS2) span = CAPS2;
    if (span > CAP3 - base0) span = CAP3 - base0;
    const unsigned* sb = srt2 + (size_t)B * CAPC + base0;
    for (int i = tid; i < span; i += 256) srt[i] = sb[i];
    __syncthreads();

    const uint4* h4 = (const uint4*)h;                   // h row = 16 uint4
    int wave = tid >> 6, lane = tid & 63;
    int q = lane >> 4, c16 = lane & 15;
    int m = *flag;

    for (int t = 0; t < 8; ++t) {                        // 8 nodes per wave
        int nl = wave * 8 + t;
        int n = n0 + nl;
        int o = l_ofs[nl] - base0;
        int cnt = l_deg[nl];
        int e_end = o + cnt; if (e_end > span) e_end = span;

        uint4 sp = make_uint4(0u, 0u, 0u, 0u);
        if (q == 0) sp = h4[(size_t)n * 16 + c16];       // hoisted self term

        float acc[8] = {0.f, 0.f, 0.f, 0.f, 0.f, 0.f, 0.f, 0.f};
        int j = o + q;
        for (; j + 4 < e_end; j += 8) {                  // ILP-2
            unsigned s0 = srt[j];
            unsigned s1 = srt[j + 4];
            uint4 p0 = h4[(size_t)s0 * 16 + c16];
            uint4 p1 = h4[(size_t)s1 * 16 + c16];
            float w0 = dis[s0], w1 = dis[s1];
            acc[0] += w0 * bflo(p0.x); acc[1] += w0 * bfhi(p0.x);
            acc[2] += w0 * bflo(p0.y); acc[3] += w0 * bfhi(p0.y);
            acc[4] += w0 * bflo(p0.z); acc[5] += w0 * bfhi(p0.z);
            acc[6] += w0 * bflo(p0.w); acc[7] += w0 * bfhi(p0.w);
            acc[0] += w1 * bflo(p1.x); acc[1] += w1 * bfhi(p1.x);
            acc[2] += w1 * bflo(p1.y); acc[3] += w1 * bfhi(p1.y);
            acc[4] += w1 * bflo(p1.z); acc[5] += w1 * bfhi(p1.z);
            acc[6] += w1 * bflo(p1.w); acc[7] += w1 * bfhi(p1.w);
        }
        if (j < e_end) {
            unsigned s0 = srt[j];
            uint4 p0 = h4[(size_t)s0 * 16 + c16];
            float w0 = dis[s0];
            acc[0] += w0 * bflo(p0.x); acc[1] += w0 * bfhi(p0.x);
            acc[2] += w0 * bflo(p0.y); acc[3] += w0 * bfhi(p0.y);
            acc[4] += w0 * bflo(p0.z); acc[5] += w0 * bfhi(p0.z);
            acc[6] += w0 * bflo(p0.w); acc[7] += w0 * bfhi(p0.w);
        }
        #pragma unroll
        for (int i = 0; i < 8; ++i) {
            acc[i] += __shfl_xor(acc[i], 16);
            acc[i] += __shfl_xor(acc[i], 32);
        }

        if (q == 0) {
            float dn = rsqrtf((float)(cnt + 1));         // == dis[n]
            float v[8];
            v[0] = fmaxf(dn * (acc[0] + dn * bflo(sp.x)) + lbias[c16 * 8 + 0], 0.f);
            v[1] = fmaxf(dn * (acc[1] + dn * bfhi(sp.x)) + lbias[c16 * 8 + 1], 0.f);
            v[2] = fmaxf(dn * (acc[2] + dn * bflo(sp.y)) + lbias[c16 * 8 + 2], 0.f);
            v[3] = fmaxf(dn * (acc[3] + dn * bfhi(sp.y)) + lbias[c16 * 8 + 3], 0.f);
            v[4] = fmaxf(dn * (acc[4] + dn * bflo(sp.z)) + lbias[c16 * 8 + 4], 0.f);
            v[5] = fmaxf(dn * (acc[5] + dn * bfhi(sp.z)) + lbias[c16 * 8 + 5], 0.f);
            v[6] = fmaxf(dn * (acc[6] + dn * bflo(sp.w)) + lbias[c16 * 8 + 6], 0.f);
            v[7] = fmaxf(dn * (acc[7] + dn * bfhi(sp.w)) + lbias[c16 * 8 + 7], 0.f);
            if (m) {
                uint4 pk;
                pk.x = ((unsigned)f2bf(v[1]) << 16) | f2bf(v[0]);
                pk.y = ((unsigned)f2bf(v[3]) << 16) | f2bf(v[2]);
                pk.z = ((unsigned)f2bf(v[5]) << 16) | f2bf(v[4]);
                pk.w = ((unsigned)f2bf(v[7]) << 16) | f2bf(v[6]);
                ((uint4*)out)[(size_t)n * 16 + c16] = pk;
            } else {
                float4 f0 = make_float4(v[0], v[1], v[2], v[3]);
                float4 f1 = make_float4(v[4], v[5], v[6], v[7]);
                float4* of = (float4*)((float*)out + (size_t)n * D + c16 * 8);
                of[0] = f0; of[1] = f1;
            }
        }
    }
}

extern "C" void kernel_launch(void* const* d_in, const int* in_sizes, int n_in,
                              void* d_out, int out_size, void* d_ws, size_t ws_size,
                              hipStream_t stream) {
    const void* x = nullptr; const int* ei = nullptr;
    const void* W = nullptr; const void* b = nullptr;
    for (int i = 0; i < n_in; ++i) {
        if      (in_sizes[i] == N_NODES * D) x  = d_in[i];
        else if (in_sizes[i] == 2 * N_EDGES) ei = (const int*)d_in[i];
        else if (in_sizes[i] == D * D)       W  = d_in[i];
        else if (in_sizes[i] == D)           b  = d_in[i];
    }
    if (!x || !ei || !W || !b) {
        x = d_in[0]; ei = (const int*)d_in[1]; W = d_in[2]; b = d_in[3];
    }
    const int* src = ei;            // edge_index[0]
    const int* dst = ei + N_EDGES;  // edge_index[1]

    // ws: flag 16B | ccnt NC*16 ints | bfv 128 f32 | Wbf 16384 u16 (32KB) |
    //     deg NC*512 | nodeofs NC*512 | dis NC*512 f32 |
    //     recg NC*CAPC u32 (9.6MB, re-sorted in place) | h N*D bf16
    char* ws = (char*)d_ws;
    int*      flag    = (int*)ws;
    int*      ccnt    = (int*)(ws + 16);
    float*    bfv     = (float*)(ccnt + NC * CCSTRIDE);
    unsigned short* Wbf = (unsigned short*)(bfv + D);
    int*      deg     = (int*)(Wbf + D * D);
    int*      nodeofs = deg + NC * 512;
    float*    dis     = (float*)(nodeofs + NC * 512);
    unsigned* recg    = (unsigned*)(dis + NC * 512);
    unsigned short* h = (unsigned short*)(recg + (size_t)NC * CAPC);

    probe_convert_kernel<<<1, 256, 0, stream>>>((const unsigned int*)x, b, W,
                                                flag, bfv, Wbf, ccnt);

    binD_kernel<<<BIND_BLOCKS, 512, 0, stream>>>(src, dst, ccnt, recg);

    gemm_kernel<<<GEMM_BLOCKS, 512, 0, stream>>>(x, Wbf, flag, h);

    sortdeg_kernel<<<NC, 512, 0, stream>>>(recg, ccnt, deg, nodeofs, dis);

    agg5_kernel<<<AGG_HALF, 256, 0, stream>>>(recg, nodeofs, deg, dis, bfv, flag, h,
                                              d_out, 0);
    agg5_kernel<<<NSUB2 - AGG_HALF, 256, 0, stream>>>(recg, nodeofs, deg, dis, bfv,
                                                      flag, h, d_out, AGG_HALF);
}